// Round 12
// baseline (15.905 us; speedup 1.0000x reference)
//
#include <hip/hip_runtime.h>

#define NPTS 8192
#define G 4096                      // buckets per plane
#define LOF (-6.0f)
#define BWF (12.0f / (float)G)      // bucket width
#define INVW ((float)G / 12.0f)
#define BTHREADS 1024
#define VPT (NPTS / BTHREADS)       // 8 values per build thread
#define QTHREADS 256
#define QSLICES 32                  // query slices per plane
#define QBLKS (6 * QSLICES)         // 192
#define KWIN 16                     // initial one-sided window (positions)
#define KEXP 32                     // expansion step (positions)

// ws float layout: sorted[6][NPTS] | start[6][G+1] | qv[6][NPTS] | partials[QBLKS]
#define WS_SORTED 0
#define WS_START  (6 * NPTS)
#define WS_QV     (WS_START + 6 * (G + 1))
#define WS_PART   (WS_QV + 6 * NPTS)

__device__ __forceinline__ int bucket_of(float v) {
    int b = (int)((v - LOF) * INVW);
    return min(max(b, 0), G - 1);
}

// K1: one block per plane (6 blocks x 1024 thr). Counting-sort the plane's
// 8192 values into global CSR (sorted + start) via LDS hist -> shfl scan ->
// LDS scatter -> coalesced float4 writeback. Also writes the deinterleaved
// query copy qv so K2's x-load is a single coalesced dword.
__global__ __launch_bounds__(BTHREADS) void build_kernel(
    const float* __restrict__ pred, const float* __restrict__ target,
    float* __restrict__ sorted, int* __restrict__ start,
    float* __restrict__ qv)
{
    const int p   = blockIdx.x;       // 0..5
    const int arr = p / 3, ch = p - arr * 3;
    const float* src = arr ? target : pred;

    __shared__ unsigned hist[G];      // 16 KB
    __shared__ unsigned curs[G];      // 16 KB
    __shared__ __align__(16) float sv[NPTS];  // 32 KB sorted stage
    __shared__ unsigned wtot[BTHREADS / 64];

    const int t = threadIdx.x, lane = t & 63, wave = t >> 6;

    float v[VPT];
    #pragma unroll
    for (int j = 0; j < VPT; ++j)
        v[j] = src[(t + j * BTHREADS) * 3 + ch];

    #pragma unroll
    for (int i = t; i < G; i += BTHREADS) hist[i] = 0u;
    __syncthreads();

    #pragma unroll
    for (int j = 0; j < VPT; ++j) {
        qv[p * NPTS + t + j * BTHREADS] = v[j];       // coalesced
        atomicAdd(&hist[bucket_of(v[j])], 1u);
    }
    __syncthreads();

    // exclusive scan over G bins; 4 bins/thread
    const int BPT = G / BTHREADS;
    unsigned cnt[BPT], tsum = 0;
    #pragma unroll
    for (int j = 0; j < BPT; ++j) { cnt[j] = hist[t * BPT + j]; tsum += cnt[j]; }

    unsigned inc = tsum;
    #pragma unroll
    for (int off = 1; off < 64; off <<= 1) {
        unsigned n = __shfl_up(inc, off, 64);
        if (lane >= off) inc += n;
    }
    if (lane == 63) wtot[wave] = inc;
    __syncthreads();
    unsigned woff = 0;
    for (int w = 0; w < wave; ++w) woff += wtot[w];
    unsigned run = woff + (inc - tsum);

    #pragma unroll
    for (int j = 0; j < BPT; ++j) {
        curs[t * BPT + j] = run;
        start[p * (G + 1) + t * BPT + j] = (int)run;
        run += cnt[j];
    }
    if (t == 0) start[p * (G + 1) + G] = NPTS;
    __syncthreads();

    #pragma unroll
    for (int j = 0; j < VPT; ++j) {
        const unsigned pos = atomicAdd(&curs[bucket_of(v[j])], 1u);
        sv[pos] = v[j];                // intra-bucket order irrelevant (exact min)
    }
    __syncthreads();

    // coalesced float4 writeback of the sorted plane
    #pragma unroll
    for (int j = 0; j < NPTS / 4 / BTHREADS * 4; ++j) { }  // (no-op; keep simple below)
    for (int i = t; i < NPTS / 4; i += BTHREADS)
        ((float4*)(sorted + p * NPTS))[i] = ((const float4*)sv)[i];
}

// K2: 192 blocks x 256 thr = 6 planes x 32 slices x 256 queries. Stage the
// candidate plane's sorted array into LDS (coalesced float4), read the two
// CSR starts from L2-hot global, then the proven exact window-scan from LDS.
__global__ __launch_bounds__(QTHREADS) void query_kernel(
    const float* __restrict__ qv,
    const float* __restrict__ sorted, const int* __restrict__ start,
    float* __restrict__ partials)
{
    const int b = blockIdx.x;
    const int qp = b >> 5, s = b & (QSLICES - 1);   // query plane, slice
    const int cp = (qp + 3) % 6;                    // candidate plane

    __shared__ __align__(16) float sv[NPTS];        // 32 KB
    const int t = threadIdx.x;

    const float x = qv[qp * NPTS + s * QTHREADS + t];   // coalesced

    const float4* src4 = (const float4*)(sorted + cp * NPTS);
    #pragma unroll
    for (int j = 0; j < NPTS / 4 / QTHREADS; ++j)       // 8 iters
        ((float4*)sv)[t + j * QTHREADS] = src4[t + j * QTHREADS];

    const int* st = start + cp * (G + 1);
    const int bx = bucket_of(x);
    const int p0 = st[bx], p1 = st[bx + 1];             // L2-hot global
    __syncthreads();

    int lo = max(p0 - KWIN, 0) & ~3;
    int hi = min(p1 + KWIN, NPTS);
    hi = (hi + 3) & ~3;

    const float4* c4 = (const float4*)sv;
    float m0 = 3.0e38f, m1 = 3.0e38f;
    for (int k = lo >> 2; k < (hi >> 2); ++k) {
        const float4 c = c4[k];
        m0 = fminf(m0, fminf(fabsf(x - c.x), fabsf(x - c.y)));
        m1 = fminf(m1, fminf(fabsf(x - c.z), fabsf(x - c.w)));
    }
    float m = fminf(m0, m1);

    // unscanned-lower values < upper edge of bucket(sv[lo]);
    // unscanned-higher values >= lower edge of bucket(sv[hi-1]).
    float bl = (lo == 0)    ? 3.0e38f
             : x - (LOF + (float)(bucket_of(sv[lo]) + 1) * BWF);
    float br = (hi >= NPTS) ? 3.0e38f
             : (LOF + (float)bucket_of(sv[hi - 1]) * BWF) - x;

    while (m > fminf(bl, br)) {       // rare; LDS-cheap
        if (bl <= br) {
            const int nlo = max(lo - KEXP, 0);
            for (int k = nlo >> 2; k < (lo >> 2); ++k) {
                const float4 c = c4[k];
                m = fminf(m, fminf(fminf(fabsf(x - c.x), fabsf(x - c.y)),
                                   fminf(fabsf(x - c.z), fabsf(x - c.w))));
            }
            lo = nlo;
            bl = (lo == 0) ? 3.0e38f
               : x - (LOF + (float)(bucket_of(sv[lo]) + 1) * BWF);
        } else {
            const int nhi = min(hi + KEXP, NPTS);
            for (int k = hi >> 2; k < (nhi >> 2); ++k) {
                const float4 c = c4[k];
                m = fminf(m, fminf(fminf(fabsf(x - c.x), fabsf(x - c.y)),
                                   fminf(fabsf(x - c.z), fabsf(x - c.w))));
            }
            hi = nhi;
            br = (hi >= NPTS) ? 3.0e38f
               : (LOF + (float)bucket_of(sv[hi - 1]) * BWF) - x;
        }
    }

    // block sum (fixed order -> deterministic), plain store
    float sum = m;
    #pragma unroll
    for (int off = 32; off > 0; off >>= 1)
        sum += __shfl_down(sum, off, 64);
    __shared__ float wsum[QTHREADS / 64];
    if ((t & 63) == 0) wsum[t >> 6] = sum;
    __syncthreads();
    if (t == 0) {
        float tot = 0.f;
        #pragma unroll
        for (int w = 0; w < QTHREADS / 64; ++w) tot += wsum[w];
        partials[b] = tot;
    }
}

// K3: one wave sums the 192 partials -> out = sum / NPTS.
__global__ __launch_bounds__(64) void final_kernel(
    const float* __restrict__ partials, float* __restrict__ out)
{
    const int t = threadIdx.x;
    float s = partials[t] + partials[t + 64] + partials[t + 128];
    #pragma unroll
    for (int off = 32; off > 0; off >>= 1)
        s += __shfl_down(s, off, 64);
    if (t == 0) out[0] = s * (1.0f / NPTS);
}

extern "C" void kernel_launch(void* const* d_in, const int* in_sizes, int n_in,
                              void* d_out, int out_size, void* d_ws, size_t ws_size,
                              hipStream_t stream) {
    const float* pred   = (const float*)d_in[0];
    const float* target = (const float*)d_in[1];
    float* out = (float*)d_out;
    float* wsf = (float*)d_ws;

    float* sorted   = wsf + WS_SORTED;
    int*   startp   = (int*)(wsf + WS_START);
    float* qv       = wsf + WS_QV;
    float* partials = wsf + WS_PART;

    build_kernel<<<6, BTHREADS, 0, stream>>>(pred, target, sorted, startp, qv);
    query_kernel<<<QBLKS, QTHREADS, 0, stream>>>(qv, sorted, startp, partials);
    final_kernel<<<1, 64, 0, stream>>>(partials, out);
}